// Round 23
// baseline (149.574 us; speedup 1.0000x reference)
//
#include <hip/hip_runtime.h>
#include <stdint.h>

typedef __bf16 bf16x8 __attribute__((ext_vector_type(8)));
typedef short s16x8 __attribute__((ext_vector_type(8)));
typedef short s16x4 __attribute__((ext_vector_type(4)));
typedef float f32x4 __attribute__((ext_vector_type(4)));
typedef float f32x16 __attribute__((ext_vector_type(16)));
typedef unsigned short u16;

#define K_DIM 1024

static __device__ __forceinline__ u16 f2bf(float f) {
    uint32_t x = __float_as_uint(f);
    x += 0x7fffu + ((x >> 16) & 1u);
    return (u16)(x >> 16);
}

static __device__ __forceinline__ f32x4 mfma16(s16x8 a, s16x8 b, f32x4 c) {
    return __builtin_amdgcn_mfma_f32_16x16x32_bf16(
        __builtin_bit_cast(bf16x8, a), __builtin_bit_cast(bf16x8, b), c, 0, 0, 0);
}

static __device__ __forceinline__ f32x16 mfma32(s16x8 a, s16x8 b, f32x16 c) {
    return __builtin_amdgcn_mfma_f32_32x32x16_bf16(
        __builtin_bit_cast(bf16x8, a), __builtin_bit_cast(bf16x8, b), c, 0, 0, 0);
}

static __device__ __forceinline__ void gload16(const u16* g, u16* l) {
    __builtin_amdgcn_global_load_lds(
        (const __attribute__((address_space(1))) void*)g,
        (__attribute__((address_space(3))) void*)l,
        16, 0, 0);
}

static __device__ __forceinline__ uint32_t cvt_pk_bf16(float lo, float hi) {
    uint32_t r;
    asm("v_cvt_pk_bf16_f32 %0, %1, %2" : "=v"(r) : "v"(lo), "v"(hi));
    return r;
}

static __device__ __forceinline__ void pswap(uint32_t& a, uint32_t& b) {
    asm volatile("v_permlane32_swap_b32 %0, %1" : "+v"(a), "+v"(b));
}

static __device__ __forceinline__ float fexp2(float x) {
#if __has_builtin(__builtin_amdgcn_exp2f)
    return __builtin_amdgcn_exp2f(x);
#else
    return __expf(x * 0.69314718056f);
#endif
}

// ---------------- fused fp32 -> bf16 conversion (one launch) ----------------
__global__ void cvt_all(const float* __restrict__ x, const float* __restrict__ wq,
                        const float* __restrict__ wo,
                        u16* __restrict__ xb, u16* __restrict__ wqb,
                        u16* __restrict__ wob) {
    const int stride = gridDim.x * blockDim.x;
    const int tid = blockIdx.x * blockDim.x + threadIdx.x;
    for (int i = tid; i < 2097152; i += stride) {
        float4 f = ((const float4*)x)[i];
        ushort4 o;
        o.x = f2bf(f.x); o.y = f2bf(f.y); o.z = f2bf(f.z); o.w = f2bf(f.w);
        ((ushort4*)xb)[i] = o;
    }
    for (int i = tid; i < 786432; i += stride) {
        float4 f = ((const float4*)wq)[i];
        ushort4 o;
        o.x = f2bf(f.x); o.y = f2bf(f.y); o.z = f2bf(f.z); o.w = f2bf(f.w);
        ((ushort4*)wqb)[i] = o;
    }
    for (int i = tid; i < 262144; i += stride) {
        float4 f = ((const float4*)wo)[i];
        ushort4 o;
        o.x = f2bf(f.x); o.y = f2bf(f.y); o.z = f2bf(f.z); o.w = f2bf(f.w);
        ((ushort4*)wob)[i] = o;
    }
}

// ---------------- QKV projection GEMM (r15/r18 known-good) ----------------
__global__ __launch_bounds__(256) void gemm_qkv(
    const u16* __restrict__ A, const u16* __restrict__ B,
    const float* __restrict__ bias,
    u16* __restrict__ qo, u16* __restrict__ ko, u16* __restrict__ vto)
{
    __shared__ u16 smem[32768];
    u16* ct = smem;
    const int tid = threadIdx.x;
    const int w = tid >> 6, l = tid & 63;
    const int lr = l & 15, lc = l >> 4;

    const int f = blockIdx.y * 64 + blockIdx.x;
    const int c = f & 7, j = f >> 3;
    const int m0 = (c * 8 + (j & 7)) * 128;
    const int n0 = (j >> 3) * 128;
    const int wm = (w >> 1) * 64, wn = (w & 1) * 64;

    const int srow = w * 8 + (l >> 3);
    const int scol = ((l & 7) ^ (l >> 3)) * 8;
    const u16* gA = A + (size_t)(m0 + srow) * K_DIM + scol;
    const u16* gB = B + (size_t)(n0 + srow) * K_DIM + scol;

    f32x4 acc[4][4] = {};

    auto stage = [&](int k0, int buf) {
        u16* base = smem + buf * 16384;
        #pragma unroll
        for (int g = 0; g < 4; ++g) {
            gload16(gA + (size_t)g * 32 * K_DIM + k0, base + (g * 32 + w * 8) * 64);
            gload16(gB + (size_t)g * 32 * K_DIM + k0, base + 8192 + (g * 32 + w * 8) * 64);
        }
    };

    stage(0, 0);
    int cur = 0;

    for (int k0 = 0; k0 < K_DIM; k0 += 64) {
        __syncthreads();
        if (k0 + 64 < K_DIM) stage(k0 + 64, cur ^ 1);
        const u16* As = smem + cur * 16384;
        const u16* Bs = As + 8192;
        #pragma unroll
        for (int kk = 0; kk < 2; ++kk) {
            s16x8 a[4], b[4];
            #pragma unroll
            for (int i = 0; i < 4; ++i) {
                const int row = wm + i * 16 + lr;
                a[i] = *(const s16x8*)&As[row * 64 + ((kk * 32 + lc * 8) ^ ((row & 7) * 8))];
            }
            #pragma unroll
            for (int jn = 0; jn < 4; ++jn) {
                const int row = wn + jn * 16 + lr;
                b[jn] = *(const s16x8*)&Bs[row * 64 + ((kk * 32 + lc * 8) ^ ((row & 7) * 8))];
            }
            #pragma unroll
            for (int i = 0; i < 4; ++i)
                #pragma unroll
                for (int jn = 0; jn < 4; ++jn)
                    acc[i][jn] = mfma16(a[i], b[jn], acc[i][jn]);
        }
        cur ^= 1;
    }

    const int sec = n0 >> 10;
    const int bb = m0 >> 11, s0 = m0 & 2047;

    if (sec < 2) {
        #pragma unroll
        for (int jn = 0; jn < 4; ++jn) {
            const int n = n0 + wn + jn * 16 + lr;
            const float bv = bias[n];
            const int h = (n & 1023) >> 6, d = n & 63;
            #pragma unroll
            for (int i = 0; i < 4; ++i) {
                #pragma unroll
                for (int r = 0; r < 4; ++r) {
                    const int m = m0 + wm + i * 16 + lc * 4 + r;
                    const int s = m & 2047;
                    float v = acc[i][jn][r] + bv;
                    if (sec == 0)
                        qo[((size_t)((bb * 16 + h) * 2048 + s)) * 64 + d] = f2bf(v * 0.18033688f);
                    else
                        ko[((size_t)((bb * 16 + h) * 2048 + s)) * 64 + d] = f2bf(v);
                }
            }
        }
    } else {
        __syncthreads();
        #pragma unroll
        for (int jj = 0; jj < 4; ++jj) {
            const int nl = (wn >> 6) * 16 + lr;
            const float bv = bias[n0 + wn + jj * 16 + lr];
            #pragma unroll
            for (int i = 0; i < 4; ++i) {
                const int mloc = wm + i * 16 + lc * 4;
                uint2 pk;
                pk.x = cvt_pk_bf16(acc[i][jj][0] + bv, acc[i][jj][1] + bv);
                pk.y = cvt_pk_bf16(acc[i][jj][2] + bv, acc[i][jj][3] + bv);
                *(s16x4*)&ct[nl * 136 + mloc] = __builtin_bit_cast(s16x4, pk);
            }
            __syncthreads();
            #pragma unroll
            for (int rep = 0; rep < 2; ++rep) {
                const int col = tid >> 3;
                const int seg = (tid & 7) + rep * 8;
                const int nn = n0 + (col >> 4) * 64 + jj * 16 + (col & 15);
                const int h = (nn & 1023) >> 6, d = nn & 63;
                const int mo = seg * 8;
                s16x8 v = *(const s16x8*)&ct[col * 136 + mo];
                *(s16x8*)&vto[((size_t)((bb * 16 + h) * 64 + d)) * 2048 + s0 + mo] = v;
            }
            __syncthreads();
        }
    }
}

// ---------------- flash attention (causal, static-max, swapped QK^T, 32x32 MFMA) --------
// r21 structure (in-register P via cvt_pk + permlane32_swap, 2-buffer dbuf
// staging, 32KB LDS) UN-PAIRED: one block per 128-row chunk, grid (64,16)
// longest-first, launch_bounds(256,4) -> 4 blocks/CU = 4 waves/SIMD so the
// per-wave serial chains (QK -> exp2 -> pack -> PV) overlap across waves.
__global__ __launch_bounds__(256, 4) void attn_fwd(
    const u16* __restrict__ q, const u16* __restrict__ k,
    const u16* __restrict__ vt, u16* __restrict__ ao)
{
    __shared__ u16 kt[2][8 * 512];     // frag (jx*4+kk): K[c0+jx*32+(l&31)][kk*16+hl*8 ..+8)
    __shared__ u16 vtl[2][8 * 512];    // frag (jd*4+ks): V^T[jd*32+(l&31)][c0+ks*16+hl*8 ..+8)
    const int w = threadIdx.x >> 6, l = threadIdx.x & 63;
    const int l31 = l & 31, hl = l >> 5;
    const int bh = blockIdx.x;
    const int C = 15 - blockIdx.y;            // longest blocks dispatch first
    const u16* qp = q + (size_t)bh * 2048 * 64;
    const u16* kp = k + (size_t)bh * 2048 * 64;
    const u16* vp = vt + (size_t)bh * 64 * 2048;
    const int bb = bh >> 4, hd = bh & 15;

    const int q0 = C * 128 + w * 32;
    const int nb = 2 * C + 2;
    const int diag = 2 * C + (w >> 1);

    s16x8 aQ[4];
    #pragma unroll
    for (int kk = 0; kk < 4; ++kk)
        aQ[kk] = *(const s16x8*)&qp[(q0 + l31) * 64 + kk * 16 + hl * 8];

    f32x16 O[2] = {};
    f32x16 ls16 = {};

    auto stage = [&](int t, int buf) {
        const int c0 = t * 64;
        if (w < 2) {
            #pragma unroll
            for (int gi = 0; gi < 4; ++gi) {
                const int g = w * 4 + gi;
                const int jx = g >> 2, kk = g & 3;
                gload16(kp + (c0 + jx * 32 + l31) * 64 + kk * 16 + hl * 8,
                        &kt[buf][g * 512]);
            }
        } else {
            #pragma unroll
            for (int gi = 0; gi < 4; ++gi) {
                const int g = (w - 2) * 4 + gi;
                const int jd = g >> 2, ks = g & 3;
                gload16(vp + (jd * 32 + l31) * 2048 + c0 + ks * 16 + hl * 8,
                        &vtl[buf][g * 512]);
            }
        }
    };

    stage(0, 0);
    int cur = 0;

    for (int t = 0; t < nb; ++t) {
        __syncthreads();
        if (t + 1 < nb) stage(t + 1, cur ^ 1);

        if (t <= diag) {
            const int c0 = t * 64;
            f32x16 s[2] = {};
            __builtin_amdgcn_s_setprio(1);
            #pragma unroll
            for (int jx = 0; jx < 2; ++jx)
                #pragma unroll
                for (int kk = 0; kk < 4; ++kk) {
                    s16x8 kf = *(const s16x8*)&kt[cur][(jx * 4 + kk) * 512 + l * 8];
                    s[jx] = mfma32(kf, aQ[kk], s[jx]);
                }
            __builtin_amdgcn_s_setprio(0);
            if (t == diag) {
                const int qrow = q0 + l31;
                #pragma unroll
                for (int jx = 0; jx < 2; ++jx)
                    #pragma unroll
                    for (int reg = 0; reg < 16; ++reg) {
                        const int kv = c0 + jx * 32 + (reg & 3) + 8 * (reg >> 2) + 4 * hl;
                        if (kv > qrow) s[jx][reg] = -1e30f;
                    }
            }
            #pragma unroll
            for (int jx = 0; jx < 2; ++jx)
                #pragma unroll
                for (int reg = 0; reg < 16; ++reg)
                    s[jx][reg] = fexp2(s[jx][reg]);
            ls16 += s[0] + s[1];
            s16x8 ap[4];
            #pragma unroll
            for (int ks = 0; ks < 4; ++ks) {
                const int jxs = ks >> 1, b8 = (ks & 1) * 8;
                uint32_t XA = cvt_pk_bf16(s[jxs][b8 + 0], s[jxs][b8 + 1]);
                uint32_t XB = cvt_pk_bf16(s[jxs][b8 + 2], s[jxs][b8 + 3]);
                uint32_t YA = cvt_pk_bf16(s[jxs][b8 + 4], s[jxs][b8 + 5]);
                uint32_t YB = cvt_pk_bf16(s[jxs][b8 + 6], s[jxs][b8 + 7]);
                pswap(XA, YA);
                pswap(XB, YB);
                uint4 wds = make_uint4(XA, XB, YA, YB);
                ap[ks] = __builtin_bit_cast(s16x8, wds);
            }
            __builtin_amdgcn_s_setprio(1);
            #pragma unroll
            for (int jd = 0; jd < 2; ++jd)
                #pragma unroll
                for (int ks = 0; ks < 4; ++ks) {
                    s16x8 vf = *(const s16x8*)&vtl[cur][(jd * 4 + ks) * 512 + l * 8];
                    O[jd] = mfma32(ap[ks], vf, O[jd]);
                }
            __builtin_amdgcn_s_setprio(0);
        }
        cur ^= 1;
    }

    float t2 = 0.f;
    #pragma unroll
    for (int e = 0; e < 16; ++e) t2 += ls16[e];
    t2 += __shfl_xor(t2, 32);
    const float lsr = 1.0f / t2;

    float invr[16];
    #pragma unroll
    for (int reg = 0; reg < 16; ++reg)
        invr[reg] = __shfl(lsr, (reg & 3) + 8 * (reg >> 2) + 4 * hl);

    #pragma unroll
    for (int jd = 0; jd < 2; ++jd)
        #pragma unroll
        for (int reg = 0; reg < 16; ++reg) {
            const int qr = (reg & 3) + 8 * (reg >> 2) + 4 * hl;
            ao[((size_t)(bb * 2048 + q0 + qr)) * 1024 + hd * 64 + jd * 32 + l31] =
                f2bf(O[jd][reg] * invr[reg]);
        }
}

// ---------------- output projection GEMM (r15/r18 known-good) ----------------
__global__ __launch_bounds__(256) void gemm_out(
    const u16* __restrict__ A, const u16* __restrict__ B,
    const float* __restrict__ bias, float* __restrict__ out)
{
    __shared__ u16 smem[32768];
    const int tid = threadIdx.x;
    const int w = tid >> 6, l = tid & 63;
    const int lr = l & 15, lc = l >> 4;

    const int f = blockIdx.y * 64 + blockIdx.x;
    const int c = f & 7, j = f >> 3;
    const int m0 = (c * 8 + (j & 7)) * 128;
    const int n0 = (j >> 3) * 128;
    const int wm = (w >> 1) * 64, wn = (w & 1) * 64;

    const int srow = w * 8 + (l >> 3);
    const int scol = ((l & 7) ^ (l >> 3)) * 8;
    const u16* gA = A + (size_t)(m0 + srow) * K_DIM + scol;
    const u16* gB = B + (size_t)(n0 + srow) * K_DIM + scol;

    f32x4 acc[4][4] = {};

    auto stage = [&](int k0, int buf) {
        u16* base = smem + buf * 16384;
        #pragma unroll
        for (int g = 0; g < 4; ++g) {
            gload16(gA + (size_t)g * 32 * K_DIM + k0, base + (g * 32 + w * 8) * 64);
            gload16(gB + (size_t)g * 32 * K_DIM + k0, base + 8192 + (g * 32 + w * 8) * 64);
        }
    };

    stage(0, 0);
    int cur = 0;

    for (int k0 = 0; k0 < K_DIM; k0 += 64) {
        __syncthreads();
        if (k0 + 64 < K_DIM) stage(k0 + 64, cur ^ 1);
        const u16* As = smem + cur * 16384;
        const u16* Bs = As + 8192;
        #pragma unroll
        for (int kk = 0; kk < 2; ++kk) {
            s16x8 a[4], b[4];
            #pragma unroll
            for (int i = 0; i < 4; ++i) {
                const int row = wm + i * 16 + lr;
                a[i] = *(const s16x8*)&As[row * 64 + ((kk * 32 + lc * 8) ^ ((row & 7) * 8))];
            }
            #pragma unroll
            for (int jn = 0; jn < 4; ++jn) {
                const int row = wn + jn * 16 + lr;
                b[jn] = *(const s16x8*)&Bs[row * 64 + ((kk * 32 + lc * 8) ^ ((row & 7) * 8))];
            }
            #pragma unroll
            for (int i = 0; i < 4; ++i)
                #pragma unroll
                for (int jn = 0; jn < 4; ++jn)
                    acc[i][jn] = mfma16(a[i], b[jn], acc[i][jn]);
        }
        cur ^= 1;
    }

    #pragma unroll
    for (int jn = 0; jn < 4; ++jn) {
        const int n = n0 + wn + jn * 16 + lr;
        const float bv = bias[n];
        #pragma unroll
        for (int i = 0; i < 4; ++i) {
            #pragma unroll
            for (int r = 0; r < 4; ++r) {
                const int m = m0 + wm + i * 16 + lc * 4 + r;
                out[(size_t)m * 1024 + n] = acc[i][jn][r] + bv;
            }
        }
    }
}

// ---------------- launcher ----------------
extern "C" void kernel_launch(void* const* d_in, const int* in_sizes, int n_in,
                              void* d_out, int out_size, void* d_ws, size_t ws_size,
                              hipStream_t stream) {
    const float* x     = (const float*)d_in[0];
    const float* w_qkv = (const float*)d_in[1];
    const float* b_qkv = (const float*)d_in[2];
    const float* w_out = (const float*)d_in[3];
    const float* b_out = (const float*)d_in[4];
    float* out = (float*)d_out;

    char* ws = (char*)d_ws;
    u16* xb   = (u16*)(ws);                    // 8192x1024 bf16  (16 MB)
    u16* wqb  = (u16*)(ws + 16777216);         // 3072x1024 bf16  (6 MB)
    u16* wob  = (u16*)(ws + 23068672);         // 1024x1024 bf16  (2 MB)
    u16* qws  = (u16*)(ws + 25165824);         // [64][2048][64]  (16 MB)
    u16* kws  = (u16*)(ws + 41943040);         // [64][2048][64]  (16 MB)
    u16* vtws = (u16*)(ws + 58720256);         // [64][64][2048]  (16 MB)
    u16* attn = (u16*)(ws + 75497472);         // 8192x1024 bf16  (16 MB)

    cvt_all<<<dim3(2048), 256, 0, stream>>>(x, w_qkv, w_out, xb, wqb, wob);

    gemm_qkv<<<dim3(64, 24), 256, 0, stream>>>(xb, wqb, b_qkv, qws, kws, vtws);
    attn_fwd<<<dim3(64, 16), 256, 0, stream>>>(qws, kws, vtws, attn);
    gemm_out<<<dim3(64, 8), 256, 0, stream>>>(attn, wob, b_out, out);
}

// Round 24
// 131.917 us; speedup vs baseline: 1.1338x; 1.1338x over previous
//
#include <hip/hip_runtime.h>
#include <stdint.h>

typedef __bf16 bf16x8 __attribute__((ext_vector_type(8)));
typedef short s16x8 __attribute__((ext_vector_type(8)));
typedef short s16x4 __attribute__((ext_vector_type(4)));
typedef float f32x4 __attribute__((ext_vector_type(4)));
typedef float f32x16 __attribute__((ext_vector_type(16)));
typedef unsigned short u16;

#define K_DIM 1024

static __device__ __forceinline__ u16 f2bf(float f) {
    uint32_t x = __float_as_uint(f);
    x += 0x7fffu + ((x >> 16) & 1u);
    return (u16)(x >> 16);
}

static __device__ __forceinline__ f32x4 mfma16(s16x8 a, s16x8 b, f32x4 c) {
    return __builtin_amdgcn_mfma_f32_16x16x32_bf16(
        __builtin_bit_cast(bf16x8, a), __builtin_bit_cast(bf16x8, b), c, 0, 0, 0);
}

static __device__ __forceinline__ f32x16 mfma32(s16x8 a, s16x8 b, f32x16 c) {
    return __builtin_amdgcn_mfma_f32_32x32x16_bf16(
        __builtin_bit_cast(bf16x8, a), __builtin_bit_cast(bf16x8, b), c, 0, 0, 0);
}

static __device__ __forceinline__ void gload16(const u16* g, u16* l) {
    __builtin_amdgcn_global_load_lds(
        (const __attribute__((address_space(1))) void*)g,
        (__attribute__((address_space(3))) void*)l,
        16, 0, 0);
}

static __device__ __forceinline__ uint32_t cvt_pk_bf16(float lo, float hi) {
    uint32_t r;
    asm("v_cvt_pk_bf16_f32 %0, %1, %2" : "=v"(r) : "v"(lo), "v"(hi));
    return r;
}

static __device__ __forceinline__ void pswap(uint32_t& a, uint32_t& b) {
    asm volatile("v_permlane32_swap_b32 %0, %1" : "+v"(a), "+v"(b));
}

static __device__ __forceinline__ float fexp2(float x) {
#if __has_builtin(__builtin_amdgcn_exp2f)
    return __builtin_amdgcn_exp2f(x);
#else
    return __expf(x * 0.69314718056f);
#endif
}

// ---------------- fused fp32 -> bf16 conversion (one launch) ----------------
__global__ void cvt_all(const float* __restrict__ x, const float* __restrict__ wq,
                        const float* __restrict__ wo,
                        u16* __restrict__ xb, u16* __restrict__ wqb,
                        u16* __restrict__ wob) {
    const int stride = gridDim.x * blockDim.x;
    const int tid = blockIdx.x * blockDim.x + threadIdx.x;
    for (int i = tid; i < 2097152; i += stride) {
        float4 f = ((const float4*)x)[i];
        ushort4 o;
        o.x = f2bf(f.x); o.y = f2bf(f.y); o.z = f2bf(f.z); o.w = f2bf(f.w);
        ((ushort4*)xb)[i] = o;
    }
    for (int i = tid; i < 786432; i += stride) {
        float4 f = ((const float4*)wq)[i];
        ushort4 o;
        o.x = f2bf(f.x); o.y = f2bf(f.y); o.z = f2bf(f.z); o.w = f2bf(f.w);
        ((ushort4*)wqb)[i] = o;
    }
    for (int i = tid; i < 262144; i += stride) {
        float4 f = ((const float4*)wo)[i];
        ushort4 o;
        o.x = f2bf(f.x); o.y = f2bf(f.y); o.z = f2bf(f.z); o.w = f2bf(f.w);
        ((ushort4*)wob)[i] = o;
    }
}

// ---------------- QKV projection GEMM (r15/r18 known-good) ----------------
__global__ __launch_bounds__(256) void gemm_qkv(
    const u16* __restrict__ A, const u16* __restrict__ B,
    const float* __restrict__ bias,
    u16* __restrict__ qo, u16* __restrict__ ko, u16* __restrict__ vto)
{
    __shared__ u16 smem[32768];
    u16* ct = smem;
    const int tid = threadIdx.x;
    const int w = tid >> 6, l = tid & 63;
    const int lr = l & 15, lc = l >> 4;

    const int f = blockIdx.y * 64 + blockIdx.x;
    const int c = f & 7, j = f >> 3;
    const int m0 = (c * 8 + (j & 7)) * 128;
    const int n0 = (j >> 3) * 128;
    const int wm = (w >> 1) * 64, wn = (w & 1) * 64;

    const int srow = w * 8 + (l >> 3);
    const int scol = ((l & 7) ^ (l >> 3)) * 8;
    const u16* gA = A + (size_t)(m0 + srow) * K_DIM + scol;
    const u16* gB = B + (size_t)(n0 + srow) * K_DIM + scol;

    f32x4 acc[4][4] = {};

    auto stage = [&](int k0, int buf) {
        u16* base = smem + buf * 16384;
        #pragma unroll
        for (int g = 0; g < 4; ++g) {
            gload16(gA + (size_t)g * 32 * K_DIM + k0, base + (g * 32 + w * 8) * 64);
            gload16(gB + (size_t)g * 32 * K_DIM + k0, base + 8192 + (g * 32 + w * 8) * 64);
        }
    };

    stage(0, 0);
    int cur = 0;

    for (int k0 = 0; k0 < K_DIM; k0 += 64) {
        __syncthreads();
        if (k0 + 64 < K_DIM) stage(k0 + 64, cur ^ 1);
        const u16* As = smem + cur * 16384;
        const u16* Bs = As + 8192;
        #pragma unroll
        for (int kk = 0; kk < 2; ++kk) {
            s16x8 a[4], b[4];
            #pragma unroll
            for (int i = 0; i < 4; ++i) {
                const int row = wm + i * 16 + lr;
                a[i] = *(const s16x8*)&As[row * 64 + ((kk * 32 + lc * 8) ^ ((row & 7) * 8))];
            }
            #pragma unroll
            for (int jn = 0; jn < 4; ++jn) {
                const int row = wn + jn * 16 + lr;
                b[jn] = *(const s16x8*)&Bs[row * 64 + ((kk * 32 + lc * 8) ^ ((row & 7) * 8))];
            }
            #pragma unroll
            for (int i = 0; i < 4; ++i)
                #pragma unroll
                for (int jn = 0; jn < 4; ++jn)
                    acc[i][jn] = mfma16(a[i], b[jn], acc[i][jn]);
        }
        cur ^= 1;
    }

    const int sec = n0 >> 10;
    const int bb = m0 >> 11, s0 = m0 & 2047;

    if (sec < 2) {
        #pragma unroll
        for (int jn = 0; jn < 4; ++jn) {
            const int n = n0 + wn + jn * 16 + lr;
            const float bv = bias[n];
            const int h = (n & 1023) >> 6, d = n & 63;
            #pragma unroll
            for (int i = 0; i < 4; ++i) {
                #pragma unroll
                for (int r = 0; r < 4; ++r) {
                    const int m = m0 + wm + i * 16 + lc * 4 + r;
                    const int s = m & 2047;
                    float v = acc[i][jn][r] + bv;
                    if (sec == 0)
                        qo[((size_t)((bb * 16 + h) * 2048 + s)) * 64 + d] = f2bf(v * 0.18033688f);
                    else
                        ko[((size_t)((bb * 16 + h) * 2048 + s)) * 64 + d] = f2bf(v);
                }
            }
        }
    } else {
        __syncthreads();
        #pragma unroll
        for (int jj = 0; jj < 4; ++jj) {
            const int nl = (wn >> 6) * 16 + lr;
            const float bv = bias[n0 + wn + jj * 16 + lr];
            #pragma unroll
            for (int i = 0; i < 4; ++i) {
                const int mloc = wm + i * 16 + lc * 4;
                uint2 pk;
                pk.x = cvt_pk_bf16(acc[i][jj][0] + bv, acc[i][jj][1] + bv);
                pk.y = cvt_pk_bf16(acc[i][jj][2] + bv, acc[i][jj][3] + bv);
                *(s16x4*)&ct[nl * 136 + mloc] = __builtin_bit_cast(s16x4, pk);
            }
            __syncthreads();
            #pragma unroll
            for (int rep = 0; rep < 2; ++rep) {
                const int col = tid >> 3;
                const int seg = (tid & 7) + rep * 8;
                const int nn = n0 + (col >> 4) * 64 + jj * 16 + (col & 15);
                const int h = (nn & 1023) >> 6, d = nn & 63;
                const int mo = seg * 8;
                s16x8 v = *(const s16x8*)&ct[col * 136 + mo];
                *(s16x8*)&vto[((size_t)((bb * 16 + h) * 64 + d)) * 2048 + s0 + mo] = v;
            }
            __syncthreads();
        }
    }
}

// ---------------- flash attention (causal, static-max, swapped QK^T, 32x32 MFMA) --------
// r21 structure (in-register P via cvt_pk + permlane32_swap, 2-buffer dbuf
// staging, 32KB LDS), un-paired: one block per 128-row chunk, grid (64,16)
// longest-first. launch_bounds(256,2) keeps the natural 88-VGPR allocation
// (r23's ,4 hint caused spills); residency rises to 4 blocks/CU via the grid.
__global__ __launch_bounds__(256, 2) void attn_fwd(
    const u16* __restrict__ q, const u16* __restrict__ k,
    const u16* __restrict__ vt, u16* __restrict__ ao)
{
    __shared__ u16 kt[2][8 * 512];     // frag (jx*4+kk): K[c0+jx*32+(l&31)][kk*16+hl*8 ..+8)
    __shared__ u16 vtl[2][8 * 512];    // frag (jd*4+ks): V^T[jd*32+(l&31)][c0+ks*16+hl*8 ..+8)
    const int w = threadIdx.x >> 6, l = threadIdx.x & 63;
    const int l31 = l & 31, hl = l >> 5;
    const int bh = blockIdx.x;
    const int C = 15 - blockIdx.y;            // longest blocks dispatch first
    const u16* qp = q + (size_t)bh * 2048 * 64;
    const u16* kp = k + (size_t)bh * 2048 * 64;
    const u16* vp = vt + (size_t)bh * 64 * 2048;
    const int bb = bh >> 4, hd = bh & 15;

    const int q0 = C * 128 + w * 32;
    const int nb = 2 * C + 2;
    const int diag = 2 * C + (w >> 1);

    s16x8 aQ[4];
    #pragma unroll
    for (int kk = 0; kk < 4; ++kk)
        aQ[kk] = *(const s16x8*)&qp[(q0 + l31) * 64 + kk * 16 + hl * 8];

    f32x16 O[2] = {};
    f32x16 ls16 = {};

    auto stage = [&](int t, int buf) {
        const int c0 = t * 64;
        if (w < 2) {
            #pragma unroll
            for (int gi = 0; gi < 4; ++gi) {
                const int g = w * 4 + gi;
                const int jx = g >> 2, kk = g & 3;
                gload16(kp + (c0 + jx * 32 + l31) * 64 + kk * 16 + hl * 8,
                        &kt[buf][g * 512]);
            }
        } else {
            #pragma unroll
            for (int gi = 0; gi < 4; ++gi) {
                const int g = (w - 2) * 4 + gi;
                const int jd = g >> 2, ks = g & 3;
                gload16(vp + (jd * 32 + l31) * 2048 + c0 + ks * 16 + hl * 8,
                        &vtl[buf][g * 512]);
            }
        }
    };

    stage(0, 0);
    int cur = 0;

    for (int t = 0; t < nb; ++t) {
        __syncthreads();
        if (t + 1 < nb) stage(t + 1, cur ^ 1);

        if (t <= diag) {
            const int c0 = t * 64;
            f32x16 s[2] = {};
            __builtin_amdgcn_s_setprio(1);
            #pragma unroll
            for (int jx = 0; jx < 2; ++jx)
                #pragma unroll
                for (int kk = 0; kk < 4; ++kk) {
                    s16x8 kf = *(const s16x8*)&kt[cur][(jx * 4 + kk) * 512 + l * 8];
                    s[jx] = mfma32(kf, aQ[kk], s[jx]);
                }
            __builtin_amdgcn_s_setprio(0);
            if (t == diag) {
                const int qrow = q0 + l31;
                #pragma unroll
                for (int jx = 0; jx < 2; ++jx)
                    #pragma unroll
                    for (int reg = 0; reg < 16; ++reg) {
                        const int kv = c0 + jx * 32 + (reg & 3) + 8 * (reg >> 2) + 4 * hl;
                        if (kv > qrow) s[jx][reg] = -1e30f;
                    }
            }
            #pragma unroll
            for (int jx = 0; jx < 2; ++jx)
                #pragma unroll
                for (int reg = 0; reg < 16; ++reg)
                    s[jx][reg] = fexp2(s[jx][reg]);
            ls16 += s[0] + s[1];
            s16x8 ap[4];
            #pragma unroll
            for (int ks = 0; ks < 4; ++ks) {
                const int jxs = ks >> 1, b8 = (ks & 1) * 8;
                uint32_t XA = cvt_pk_bf16(s[jxs][b8 + 0], s[jxs][b8 + 1]);
                uint32_t XB = cvt_pk_bf16(s[jxs][b8 + 2], s[jxs][b8 + 3]);
                uint32_t YA = cvt_pk_bf16(s[jxs][b8 + 4], s[jxs][b8 + 5]);
                uint32_t YB = cvt_pk_bf16(s[jxs][b8 + 6], s[jxs][b8 + 7]);
                pswap(XA, YA);
                pswap(XB, YB);
                uint4 wds = make_uint4(XA, XB, YA, YB);
                ap[ks] = __builtin_bit_cast(s16x8, wds);
            }
            __builtin_amdgcn_s_setprio(1);
            #pragma unroll
            for (int jd = 0; jd < 2; ++jd)
                #pragma unroll
                for (int ks = 0; ks < 4; ++ks) {
                    s16x8 vf = *(const s16x8*)&vtl[cur][(jd * 4 + ks) * 512 + l * 8];
                    O[jd] = mfma32(ap[ks], vf, O[jd]);
                }
            __builtin_amdgcn_s_setprio(0);
        }
        cur ^= 1;
    }

    float t2 = 0.f;
    #pragma unroll
    for (int e = 0; e < 16; ++e) t2 += ls16[e];
    t2 += __shfl_xor(t2, 32);
    const float lsr = 1.0f / t2;

    float invr[16];
    #pragma unroll
    for (int reg = 0; reg < 16; ++reg)
        invr[reg] = __shfl(lsr, (reg & 3) + 8 * (reg >> 2) + 4 * hl);

    #pragma unroll
    for (int jd = 0; jd < 2; ++jd)
        #pragma unroll
        for (int reg = 0; reg < 16; ++reg) {
            const int qr = (reg & 3) + 8 * (reg >> 2) + 4 * hl;
            ao[((size_t)(bb * 2048 + q0 + qr)) * 1024 + hd * 64 + jd * 32 + l31] =
                f2bf(O[jd][reg] * invr[reg]);
        }
}

// ---------------- output projection GEMM (r15/r18 known-good) ----------------
__global__ __launch_bounds__(256) void gemm_out(
    const u16* __restrict__ A, const u16* __restrict__ B,
    const float* __restrict__ bias, float* __restrict__ out)
{
    __shared__ u16 smem[32768];
    const int tid = threadIdx.x;
    const int w = tid >> 6, l = tid & 63;
    const int lr = l & 15, lc = l >> 4;

    const int f = blockIdx.y * 64 + blockIdx.x;
    const int c = f & 7, j = f >> 3;
    const int m0 = (c * 8 + (j & 7)) * 128;
    const int n0 = (j >> 3) * 128;
    const int wm = (w >> 1) * 64, wn = (w & 1) * 64;

    const int srow = w * 8 + (l >> 3);
    const int scol = ((l & 7) ^ (l >> 3)) * 8;
    const u16* gA = A + (size_t)(m0 + srow) * K_DIM + scol;
    const u16* gB = B + (size_t)(n0 + srow) * K_DIM + scol;

    f32x4 acc[4][4] = {};

    auto stage = [&](int k0, int buf) {
        u16* base = smem + buf * 16384;
        #pragma unroll
        for (int g = 0; g < 4; ++g) {
            gload16(gA + (size_t)g * 32 * K_DIM + k0, base + (g * 32 + w * 8) * 64);
            gload16(gB + (size_t)g * 32 * K_DIM + k0, base + 8192 + (g * 32 + w * 8) * 64);
        }
    };

    stage(0, 0);
    int cur = 0;

    for (int k0 = 0; k0 < K_DIM; k0 += 64) {
        __syncthreads();
        if (k0 + 64 < K_DIM) stage(k0 + 64, cur ^ 1);
        const u16* As = smem + cur * 16384;
        const u16* Bs = As + 8192;
        #pragma unroll
        for (int kk = 0; kk < 2; ++kk) {
            s16x8 a[4], b[4];
            #pragma unroll
            for (int i = 0; i < 4; ++i) {
                const int row = wm + i * 16 + lr;
                a[i] = *(const s16x8*)&As[row * 64 + ((kk * 32 + lc * 8) ^ ((row & 7) * 8))];
            }
            #pragma unroll
            for (int jn = 0; jn < 4; ++jn) {
                const int row = wn + jn * 16 + lr;
                b[jn] = *(const s16x8*)&Bs[row * 64 + ((kk * 32 + lc * 8) ^ ((row & 7) * 8))];
            }
            #pragma unroll
            for (int i = 0; i < 4; ++i)
                #pragma unroll
                for (int jn = 0; jn < 4; ++jn)
                    acc[i][jn] = mfma16(a[i], b[jn], acc[i][jn]);
        }
        cur ^= 1;
    }

    #pragma unroll
    for (int jn = 0; jn < 4; ++jn) {
        const int n = n0 + wn + jn * 16 + lr;
        const float bv = bias[n];
        #pragma unroll
        for (int i = 0; i < 4; ++i) {
            #pragma unroll
            for (int r = 0; r < 4; ++r) {
                const int m = m0 + wm + i * 16 + lc * 4 + r;
                out[(size_t)m * 1024 + n] = acc[i][jn][r] + bv;
            }
        }
    }
}

// ---------------- launcher ----------------
extern "C" void kernel_launch(void* const* d_in, const int* in_sizes, int n_in,
                              void* d_out, int out_size, void* d_ws, size_t ws_size,
                              hipStream_t stream) {
    const float* x     = (const float*)d_in[0];
    const float* w_qkv = (const float*)d_in[1];
    const float* b_qkv = (const float*)d_in[2];
    const float* w_out = (const float*)d_in[3];
    const float* b_out = (const float*)d_in[4];
    float* out = (float*)d_out;

    char* ws = (char*)d_ws;
    u16* xb   = (u16*)(ws);                    // 8192x1024 bf16  (16 MB)
    u16* wqb  = (u16*)(ws + 16777216);         // 3072x1024 bf16  (6 MB)
    u16* wob  = (u16*)(ws + 23068672);         // 1024x1024 bf16  (2 MB)
    u16* qws  = (u16*)(ws + 25165824);         // [64][2048][64]  (16 MB)
    u16* kws  = (u16*)(ws + 41943040);         // [64][2048][64]  (16 MB)
    u16* vtws = (u16*)(ws + 58720256);         // [64][64][2048]  (16 MB)
    u16* attn = (u16*)(ws + 75497472);         // 8192x1024 bf16  (16 MB)

    cvt_all<<<dim3(2048), 256, 0, stream>>>(x, w_qkv, w_out, xb, wqb, wob);

    gemm_qkv<<<dim3(64, 24), 256, 0, stream>>>(xb, wqb, b_qkv, qws, kws, vtws);
    attn_fwd<<<dim3(64, 16), 256, 0, stream>>>(qws, kws, vtws, attn);
    gemm_out<<<dim3(64, 8), 256, 0, stream>>>(attn, wob, b_out, out);
}